// Round 3
// baseline (929.709 us; speedup 1.0000x reference)
//
#include <hip/hip_runtime.h>

// Problem constants
#define DD   768          // feature dim
#define BB   256          // batch
#define NN   196          // tokens per modality
#define KK1  112          // intra top-k
#define KK2  224          // inter top-k
#define RTOT (BB*3)       // 768 rows (b,modality/query)
#define CAND (2*NN)       // 392 inter candidates per query

// native clang vector for nontemporal builtins (HIP float4 is rejected)
typedef float vfloat4 __attribute__((ext_vector_type(4)));

// -------- workspace layout (bytes) --------
// Qh double[768*768] @ 0        (4,718,592)
// Td double[768*768] @ 4718592  (4,718,592)

// ---------------------------------------------------------------------------
// GEMM1: Qh[r,e] = sum_d G[r,d]*Wq[e,d] + bq[e]   (r = b*3+q, G gathered)
// 32x32 tile, ONE wave (64 thr), 4x4 microtile, LDS transposed [k][row] so
// each thread's 4 operands are one ds_read_b128. Per-output accumulation is
// one FMA per k, k ascending -> bit-identical to the previous verified GEMM.
// ---------------------------------------------------------------------------
__global__ __launch_bounds__(64) void gemm_q(
    const float* __restrict__ g0, const float* __restrict__ g1,
    const float* __restrict__ g2, const float* __restrict__ Wq,
    const float* __restrict__ bq, double* __restrict__ Qh)
{
    __shared__ float Asq[32][33];   // [k][row]
    __shared__ float Bsq[32][33];   // [k][col]
    const int t  = threadIdx.x;
    const int tx = t & 7, ty = t >> 3;
    const int i0 = blockIdx.y * 32, j0 = blockIdx.x * 32;
    double acc[4][4] = {};
    for (int kk = 0; kk < DD; kk += 32) {
        #pragma unroll
        for (int s = 0; s < 16; ++s) {
            int e = t + s * 64;
            int r = e >> 5, c = e & 31;       // r: row/col idx, c: k idx
            int row = i0 + r;
            int b = row / 3, q = row - b * 3;
            const float* gp = (q == 0) ? g0 : (q == 1) ? g1 : g2;
            Asq[c][r] = gp[b * DD + kk + c];
            Bsq[c][r] = Wq[(j0 + r) * DD + kk + c];
        }
        __syncthreads();
        #pragma unroll
        for (int k = 0; k < 32; ++k) {
            double av[4], bv[4];
            #pragma unroll
            for (int i = 0; i < 4; ++i) av[i] = (double)Asq[k][ty * 4 + i];
            #pragma unroll
            for (int j = 0; j < 4; ++j) bv[j] = (double)Bsq[k][tx * 4 + j];
            #pragma unroll
            for (int i = 0; i < 4; ++i)
                #pragma unroll
                for (int j = 0; j < 4; ++j)
                    acc[i][j] += av[i] * bv[j];
        }
        __syncthreads();
    }
    #pragma unroll
    for (int i = 0; i < 4; ++i)
        #pragma unroll
        for (int j = 0; j < 4; ++j)
            Qh[(i0 + ty * 4 + i) * DD + j0 + tx * 4 + j]
                = acc[i][j] + (double)bq[j0 + tx * 4 + j];
}

// ---------------------------------------------------------------------------
// GEMM2: Td[r,d] = sum_e Qh[r,e]*Wk[e,d]   (same structure; A is fp64)
// ---------------------------------------------------------------------------
__global__ __launch_bounds__(64) void gemm_t(
    const double* __restrict__ Qh, const float* __restrict__ Wk,
    double* __restrict__ Td)
{
    __shared__ double Ast[32][33];  // [k][row]
    __shared__ float  Bst[32][33];  // [k][col]  (Wk rows are already [k][col])
    const int t  = threadIdx.x;
    const int tx = t & 7, ty = t >> 3;
    const int i0 = blockIdx.y * 32, j0 = blockIdx.x * 32;
    double acc[4][4] = {};
    for (int kk = 0; kk < DD; kk += 32) {
        #pragma unroll
        for (int s = 0; s < 16; ++s) {
            int e = t + s * 64;
            int r = e >> 5, c = e & 31;
            Ast[c][r] = Qh[(i0 + r) * DD + kk + c];        // transpose on write
            Bst[r][c] = Wk[(kk + r) * DD + j0 + c];        // natural [k][col]
        }
        __syncthreads();
        #pragma unroll
        for (int k = 0; k < 32; ++k) {
            double av[4], bv[4];
            #pragma unroll
            for (int i = 0; i < 4; ++i) av[i] = Ast[k][ty * 4 + i];
            #pragma unroll
            for (int j = 0; j < 4; ++j) bv[j] = (double)Bst[k][tx * 4 + j];
            #pragma unroll
            for (int i = 0; i < 4; ++i)
                #pragma unroll
                for (int j = 0; j < 4; ++j)
                    acc[i][j] += av[i] * bv[j];
        }
        __syncthreads();
    }
    #pragma unroll
    for (int i = 0; i < 4; ++i)
        #pragma unroll
        for (int j = 0; j < 4; ++j)
            Td[(i0 + ty * 4 + i) * DD + j0 + tx * 4 + j] = acc[i][j];
}

// ---------------------------------------------------------------------------
// Fused score + rank + apply: one block per batch b (256 blocks x 1024 thr).
// UNCHANGED from the verified round-2 kernel (absmax 0).
// ---------------------------------------------------------------------------
__global__ __launch_bounds__(1024) void fused_score_rank_apply(
    const float* __restrict__ p0, const float* __restrict__ p1,
    const float* __restrict__ p2, const float* __restrict__ g0,
    const float* __restrict__ g1, const float* __restrict__ g2,
    const double* __restrict__ Td, float* __restrict__ out)
{
    const int b = blockIdx.x;
    __shared__ float  Gf[3][DD];        //  9.2 KB (f32 exact; cast on use)
    __shared__ double Tq[3][DD];        // 18.4 KB
    __shared__ double Li[3][NN];        //  4.7 KB intra logits
    __shared__ double Le[3][CAND];      //  9.4 KB inter logits
    __shared__ unsigned char msk[3][NN];

    // ---- phase 1: stage globals and Td rows ----
    for (int d = threadIdx.x; d < DD; d += 1024) {
        Gf[0][d] = g0[b * DD + d];
        Gf[1][d] = g1[b * DD + d];
        Gf[2][d] = g2[b * DD + d];
        Tq[0][d] = Td[(b * 3 + 0) * DD + d];
        Tq[1][d] = Td[(b * 3 + 1) * DD + d];
        Tq[2][d] = Td[(b * 3 + 2) * DD + d];
    }
    if (threadIdx.x < 3 * NN) (&msk[0][0])[threadIdx.x] = 0;
    __syncthreads();

    const int wave = threadIdx.x >> 6, lane = threadIdx.x & 63;

    // ---- phase 2: score all 588 rows, copy patch -> out on the fly ----
    for (int r = wave; r < 3 * NN; r += 16) {
        const int m = r / NN, n = r - m * NN;
        const float* pp = (m == 0) ? p0 : (m == 1) ? p1 : p2;
        const vfloat4* row = (const vfloat4*)(pp + (size_t)(b * NN + n) * DD);
        vfloat4* orow = (vfloat4*)(out + ((size_t)m * (BB * NN) + b * NN + n) * (size_t)DD);
        const int qa = (m == 0) ? 1 : 0;
        const int qb = (m == 2) ? 1 : 2;
        const int slota = m - (m > qa ? 1 : 0);
        const int slotb = m - (m > qb ? 1 : 0);
        double s0 = 0, s1 = 0, s2 = 0;
        for (int c = lane; c < DD / 4; c += 64) {
            vfloat4 v = row[c];
            __builtin_nontemporal_store(v, &orow[c]);
            const int d = c * 4;
            s0 += (double)Gf[m][d]     * (double)v[0] + (double)Gf[m][d + 1] * (double)v[1]
                + (double)Gf[m][d + 2] * (double)v[2] + (double)Gf[m][d + 3] * (double)v[3];
            s1 += Tq[qa][d]     * (double)v[0] + Tq[qa][d + 1] * (double)v[1]
                + Tq[qa][d + 2] * (double)v[2] + Tq[qa][d + 3] * (double)v[3];
            s2 += Tq[qb][d]     * (double)v[0] + Tq[qb][d + 1] * (double)v[1]
                + Tq[qb][d + 2] * (double)v[2] + Tq[qb][d + 3] * (double)v[3];
        }
        for (int off = 32; off > 0; off >>= 1) {
            s0 += __shfl_down(s0, off);
            s1 += __shfl_down(s1, off);
            s2 += __shfl_down(s2, off);
        }
        if (lane == 0) {
            Li[m][n] = s0;
            Le[qa][slota * NN + n] = s1;
            Le[qb][slotb * NN + n] = s2;
        }
    }
    __syncthreads();

    // ---- phase 3a: intra ranks (588 threads, 196-way scan, broadcast reads)
    if (threadIdx.x < 3 * NN) {
        const int m = threadIdx.x / NN, n = threadIdx.x - m * NN;
        const double v = Li[m][n];
        int rank = 0;
        for (int j = 0; j < NN; ++j) {
            double u = Li[m][j];
            rank += (u > v) || (u == v && j < n);
        }
        if (rank < KK1) msk[m][n] = 1;
    }
    // ---- phase 3b: inter ranks (1176 entries, 392-way scan) ----
    for (int t = threadIdx.x; t < 3 * CAND; t += 1024) {
        const int q = t / CAND, c = t - q * CAND;
        const double v = Le[q][c];
        int rank = 0;
        for (int j = 0; j < CAND; ++j) {
            double u = Le[q][j];
            rank += (u > v) || (u == v && j < c);
        }
        if (rank < KK2) {
            const int ma = (q == 0) ? 1 : 0;
            const int mb = (q == 2) ? 1 : 2;
            const int mm  = (c < NN) ? ma : mb;
            const int tok = (c < NN) ? c : c - NN;
            msk[mm][tok] = 1;   // only ever writes 1; benign races
        }
    }
    __syncthreads();

    // ---- phase 4: zero the unselected rows (same thread->address map as
    //      phase 2's copy, so the overwrite is program-ordered) ----
    for (int r = wave; r < 3 * NN; r += 16) {
        const int m = r / NN, n = r - m * NN;
        if (!msk[m][n]) {
            vfloat4* orow = (vfloat4*)(out + ((size_t)m * (BB * NN) + b * NN + n) * (size_t)DD);
            const vfloat4 z = {0.f, 0.f, 0.f, 0.f};
            for (int c = lane; c < DD / 4; c += 64)
                __builtin_nontemporal_store(z, &orow[c]);
        }
    }
}

extern "C" void kernel_launch(void* const* d_in, const int* in_sizes, int n_in,
                              void* d_out, int out_size, void* d_ws, size_t ws_size,
                              hipStream_t stream) {
    const float* p0 = (const float*)d_in[0];   // rgb_patches
    const float* p1 = (const float*)d_in[1];   // nir_patches
    const float* p2 = (const float*)d_in[2];   // tir_patches
    const float* g0 = (const float*)d_in[3];   // rgb_global
    const float* g1 = (const float*)d_in[4];   // nir_global
    const float* g2 = (const float*)d_in[5];   // tir_global
    const float* Wq = (const float*)d_in[6];
    const float* bq = (const float*)d_in[7];
    const float* Wk = (const float*)d_in[8];
    // d_in[9] = bk: per-(b,q)-row constant across all candidates -> cannot
    // affect top-k ordering; intentionally unused.

    char* ws = (char*)d_ws;
    double* Qh = (double*)(ws);
    double* Td = (double*)(ws + 4718592);

    dim3 ggrid(DD / 32, RTOT / 32);   // (24, 24), 64-thread blocks
    gemm_q<<<ggrid, 64, 0, stream>>>(g0, g1, g2, Wq, bq, Qh);
    gemm_t<<<ggrid, 64, 0, stream>>>(Qh, Wk, Td);
    fused_score_rank_apply<<<BB, 1024, 0, stream>>>(p0, p1, p2, g0, g1, g2, Td, (float*)d_out);
}

// Round 4
// 895.832 us; speedup vs baseline: 1.0378x; 1.0378x over previous
//
#include <hip/hip_runtime.h>

// Problem constants
#define DD   768          // feature dim
#define BB   256          // batch
#define NN   196          // tokens per modality
#define KK1  112          // intra top-k
#define KK2  224          // inter top-k
#define RTOT (BB*3)       // 768 rows (b,modality/query)
#define CAND (2*NN)       // 392 inter candidates per query
#define NSK  4            // split-K factor
#define KCH  (DD/NSK)     // 192 k per chunk
#define MAT  (DD*DD)      // 589824 elements per 768x768 matrix

// native clang vector for nontemporal builtins (HIP float4 is rejected)
typedef float vfloat4 __attribute__((ext_vector_type(4)));

// -------- workspace layout (bytes) --------
// Qh4 double[4][768*768] @ 0          (18,874,368)
// Qh  double[768*768]    @ 18874368   ( 4,718,592)
// Td4 double[4][768*768] @ 23592960   (18,874,368)
// total 42,467,328 B (~42.5 MB; harness arena is >=1 GB per the poison fills)

// ---------------------------------------------------------------------------
// GEMM1 split-K: Qh4[kc][r][e] = sum_{d in chunk kc} G[r,d]*Wq[e,d]
// Round-2 verified inner structure (32x32 tile, 256 thr, 2x2 microtile,
// k ascending). Grid (24,24,4) -> 2304 blocks, ~36 waves/CU.
// ---------------------------------------------------------------------------
__global__ __launch_bounds__(256) void gemm_q_sk(
    const float* __restrict__ g0, const float* __restrict__ g1,
    const float* __restrict__ g2, const float* __restrict__ Wq,
    double* __restrict__ Qh4)
{
    __shared__ float As[32][33];
    __shared__ float Ws[32][33];
    const int t  = threadIdx.x;
    const int tx = t & 15, ty = t >> 4;
    const int i0 = blockIdx.y * 32, j0 = blockIdx.x * 32;
    const int kc = blockIdx.z;
    double a00 = 0, a01 = 0, a10 = 0, a11 = 0;
    for (int kk = kc * KCH; kk < kc * KCH + KCH; kk += 32) {
        for (int s = 0; s < 4; ++s) {
            int idx = t + s * 256;
            int r = idx >> 5, c = idx & 31;
            int row = i0 + r;
            int b = row / 3, q = row - b * 3;
            const float* gp = (q == 0) ? g0 : (q == 1) ? g1 : g2;
            As[r][c] = gp[b * DD + kk + c];
            Ws[r][c] = Wq[(j0 + r) * DD + kk + c];
        }
        __syncthreads();
        for (int k = 0; k < 32; ++k) {
            double x0 = (double)As[ty][k],      x1 = (double)As[ty + 16][k];
            double y0 = (double)Ws[tx][k],      y1 = (double)Ws[tx + 16][k];
            a00 += x0 * y0; a01 += x0 * y1; a10 += x1 * y0; a11 += x1 * y1;
        }
        __syncthreads();
    }
    double* Q = Qh4 + (size_t)kc * MAT;
    Q[(i0 + ty) * DD + j0 + tx]           = a00;
    Q[(i0 + ty) * DD + j0 + tx + 16]      = a01;
    Q[(i0 + ty + 16) * DD + j0 + tx]      = a10;
    Q[(i0 + ty + 16) * DD + j0 + tx + 16] = a11;
}

// ---------------------------------------------------------------------------
// Reduce Qh partials (fixed order 0..3) + bias -> Qh[r][e]
// ---------------------------------------------------------------------------
__global__ __launch_bounds__(256) void reduce_q(
    const double* __restrict__ Qh4, const float* __restrict__ bq,
    double* __restrict__ Qh)
{
    const int i = blockIdx.x * 256 + threadIdx.x;   // 0..589823
    const int e = i - (i / DD) * DD;                // column = e index
    double s = ((Qh4[i] + Qh4[i + MAT]) + Qh4[i + 2 * MAT]) + Qh4[i + 3 * MAT];
    Qh[i] = s + (double)bq[e];
}

// ---------------------------------------------------------------------------
// GEMM2 split-K: Td4[kc][r][d] = sum_{e in chunk kc} Qh[r,e]*Wk[e,d]
// ---------------------------------------------------------------------------
__global__ __launch_bounds__(256) void gemm_t_sk(
    const double* __restrict__ Qh, const float* __restrict__ Wk,
    double* __restrict__ Td4)
{
    __shared__ double As[32][33];
    __shared__ float  Ws[32][33];
    const int t  = threadIdx.x;
    const int tx = t & 15, ty = t >> 4;
    const int i0 = blockIdx.y * 32, j0 = blockIdx.x * 32;
    const int kc = blockIdx.z;
    double a00 = 0, a01 = 0, a10 = 0, a11 = 0;
    for (int kk = kc * KCH; kk < kc * KCH + KCH; kk += 32) {
        for (int s = 0; s < 4; ++s) {
            int idx = t + s * 256;
            int r = idx >> 5, c = idx & 31;
            As[r][c] = Qh[(i0 + r) * DD + kk + c];
            Ws[r][c] = Wk[(kk + r) * DD + j0 + c];
        }
        __syncthreads();
        for (int k = 0; k < 32; ++k) {
            double x0 = As[ty][k],            x1 = As[ty + 16][k];
            double y0 = (double)Ws[k][tx],    y1 = (double)Ws[k][tx + 16];
            a00 += x0 * y0; a01 += x0 * y1; a10 += x1 * y0; a11 += x1 * y1;
        }
        __syncthreads();
    }
    double* T = Td4 + (size_t)kc * MAT;
    T[(i0 + ty) * DD + j0 + tx]           = a00;
    T[(i0 + ty) * DD + j0 + tx + 16]      = a01;
    T[(i0 + ty + 16) * DD + j0 + tx]      = a10;
    T[(i0 + ty + 16) * DD + j0 + tx + 16] = a11;
}

// ---------------------------------------------------------------------------
// Fused score + rank + apply: one block per batch b (256 blocks x 1024 thr).
// Identical to the verified round-2 kernel except phase 1 sums the 4 Td
// partials (fixed order) while staging Tq.
// ---------------------------------------------------------------------------
__global__ __launch_bounds__(1024) void fused_score_rank_apply(
    const float* __restrict__ p0, const float* __restrict__ p1,
    const float* __restrict__ p2, const float* __restrict__ g0,
    const float* __restrict__ g1, const float* __restrict__ g2,
    const double* __restrict__ Td4, float* __restrict__ out)
{
    const int b = blockIdx.x;
    __shared__ float  Gf[3][DD];        //  9.2 KB
    __shared__ double Tq[3][DD];        // 18.4 KB
    __shared__ double Li[3][NN];        //  4.7 KB intra logits
    __shared__ double Le[3][CAND];      //  9.4 KB inter logits
    __shared__ unsigned char msk[3][NN];

    // ---- phase 1: stage globals and reduced Td rows ----
    for (int d = threadIdx.x; d < DD; d += 1024) {
        Gf[0][d] = g0[b * DD + d];
        Gf[1][d] = g1[b * DD + d];
        Gf[2][d] = g2[b * DD + d];
        #pragma unroll
        for (int q = 0; q < 3; ++q) {
            const size_t off = (size_t)(b * 3 + q) * DD + d;
            Tq[q][d] = ((Td4[off] + Td4[off + MAT]) + Td4[off + 2 * MAT])
                     + Td4[off + 3 * MAT];
        }
    }
    if (threadIdx.x < 3 * NN) (&msk[0][0])[threadIdx.x] = 0;
    __syncthreads();

    const int wave = threadIdx.x >> 6, lane = threadIdx.x & 63;

    // ---- phase 2: score all 588 rows, copy patch -> out on the fly ----
    for (int r = wave; r < 3 * NN; r += 16) {
        const int m = r / NN, n = r - m * NN;
        const float* pp = (m == 0) ? p0 : (m == 1) ? p1 : p2;
        const vfloat4* row = (const vfloat4*)(pp + (size_t)(b * NN + n) * DD);
        vfloat4* orow = (vfloat4*)(out + ((size_t)m * (BB * NN) + b * NN + n) * (size_t)DD);
        const int qa = (m == 0) ? 1 : 0;
        const int qb = (m == 2) ? 1 : 2;
        const int slota = m - (m > qa ? 1 : 0);
        const int slotb = m - (m > qb ? 1 : 0);
        double s0 = 0, s1 = 0, s2 = 0;
        for (int c = lane; c < DD / 4; c += 64) {
            vfloat4 v = row[c];
            __builtin_nontemporal_store(v, &orow[c]);
            const int d = c * 4;
            s0 += (double)Gf[m][d]     * (double)v[0] + (double)Gf[m][d + 1] * (double)v[1]
                + (double)Gf[m][d + 2] * (double)v[2] + (double)Gf[m][d + 3] * (double)v[3];
            s1 += Tq[qa][d]     * (double)v[0] + Tq[qa][d + 1] * (double)v[1]
                + Tq[qa][d + 2] * (double)v[2] + Tq[qa][d + 3] * (double)v[3];
            s2 += Tq[qb][d]     * (double)v[0] + Tq[qb][d + 1] * (double)v[1]
                + Tq[qb][d + 2] * (double)v[2] + Tq[qb][d + 3] * (double)v[3];
        }
        for (int off = 32; off > 0; off >>= 1) {
            s0 += __shfl_down(s0, off);
            s1 += __shfl_down(s1, off);
            s2 += __shfl_down(s2, off);
        }
        if (lane == 0) {
            Li[m][n] = s0;
            Le[qa][slota * NN + n] = s1;
            Le[qb][slotb * NN + n] = s2;
        }
    }
    __syncthreads();

    // ---- phase 3a: intra ranks ----
    if (threadIdx.x < 3 * NN) {
        const int m = threadIdx.x / NN, n = threadIdx.x - m * NN;
        const double v = Li[m][n];
        int rank = 0;
        for (int j = 0; j < NN; ++j) {
            double u = Li[m][j];
            rank += (u > v) || (u == v && j < n);
        }
        if (rank < KK1) msk[m][n] = 1;
    }
    // ---- phase 3b: inter ranks ----
    for (int t = threadIdx.x; t < 3 * CAND; t += 1024) {
        const int q = t / CAND, c = t - q * CAND;
        const double v = Le[q][c];
        int rank = 0;
        for (int j = 0; j < CAND; ++j) {
            double u = Le[q][j];
            rank += (u > v) || (u == v && j < c);
        }
        if (rank < KK2) {
            const int ma = (q == 0) ? 1 : 0;
            const int mb = (q == 2) ? 1 : 2;
            const int mm  = (c < NN) ? ma : mb;
            const int tok = (c < NN) ? c : c - NN;
            msk[mm][tok] = 1;   // only ever writes 1; benign races
        }
    }
    __syncthreads();

    // ---- phase 4: zero the unselected rows ----
    for (int r = wave; r < 3 * NN; r += 16) {
        const int m = r / NN, n = r - m * NN;
        if (!msk[m][n]) {
            vfloat4* orow = (vfloat4*)(out + ((size_t)m * (BB * NN) + b * NN + n) * (size_t)DD);
            const vfloat4 z = {0.f, 0.f, 0.f, 0.f};
            for (int c = lane; c < DD / 4; c += 64)
                __builtin_nontemporal_store(z, &orow[c]);
        }
    }
}

extern "C" void kernel_launch(void* const* d_in, const int* in_sizes, int n_in,
                              void* d_out, int out_size, void* d_ws, size_t ws_size,
                              hipStream_t stream) {
    const float* p0 = (const float*)d_in[0];   // rgb_patches
    const float* p1 = (const float*)d_in[1];   // nir_patches
    const float* p2 = (const float*)d_in[2];   // tir_patches
    const float* g0 = (const float*)d_in[3];   // rgb_global
    const float* g1 = (const float*)d_in[4];   // nir_global
    const float* g2 = (const float*)d_in[5];   // tir_global
    const float* Wq = (const float*)d_in[6];
    const float* bq = (const float*)d_in[7];
    const float* Wk = (const float*)d_in[8];
    // d_in[9] = bk: per-(b,q)-row constant across all candidates -> cannot
    // affect top-k ordering; intentionally unused.

    char* ws = (char*)d_ws;
    double* Qh4 = (double*)(ws);
    double* Qh  = (double*)(ws + 18874368);
    double* Td4 = (double*)(ws + 23592960);

    dim3 ggrid(DD / 32, RTOT / 32, NSK);   // (24, 24, 4)
    gemm_q_sk<<<ggrid, 256, 0, stream>>>(g0, g1, g2, Wq, Qh4);
    reduce_q<<<MAT / 256, 256, 0, stream>>>(Qh4, bq, Qh);
    gemm_t_sk<<<ggrid, 256, 0, stream>>>(Qh, Wk, Td4);
    fused_score_rank_apply<<<BB, 1024, 0, stream>>>(p0, p1, p2, g0, g1, g2, Td4, (float*)d_out);
}

// Round 5
// 878.067 us; speedup vs baseline: 1.0588x; 1.0202x over previous
//
#include <hip/hip_runtime.h>

// Problem constants
#define DD   768          // feature dim
#define BB   256          // batch
#define NN   196          // tokens per modality
#define KK1  112          // intra top-k
#define KK2  224          // inter top-k
#define RTOT (BB*3)       // 768 rows (b,modality/query)
#define CAND (2*NN)       // 392 inter candidates per query
#define NSK  4            // split-K factor
#define KCH  (DD/NSK)     // 192 k per chunk
#define MAT  (DD*DD)      // 589824 elements per 768x768 matrix

// native clang vectors (HIP vector types rejected by nontemporal builtins)
typedef float  vfloat4  __attribute__((ext_vector_type(4)));
typedef float  vfloat2  __attribute__((ext_vector_type(2)));
typedef double vdouble2 __attribute__((ext_vector_type(2)));

// -------- workspace layout (bytes) --------
// Qh4 double[4][768*768] @ 0          (18,874,368)
// Qh  double[768*768]    @ 18874368   ( 4,718,592)
// Td4 double[4][768*768] @ 23592960   (18,874,368)

// ---------------------------------------------------------------------------
// GEMM1 split-K: Qh4[kc][r][e] = sum_{d in chunk kc} G[r,d]*Wq[e,d]
// 32x32 tile, 256 thr, 2x2 microtile, k is the fast LDS axis on BOTH
// operands; inner loop reads k-PAIRS as float2 (ds_read_b64) -> half the
// LDS instructions of round 4. FMA order per accumulator is still k
// ascending -> bit-identical results.
// ---------------------------------------------------------------------------
__global__ __launch_bounds__(256) void gemm_q_sk(
    const float* __restrict__ g0, const float* __restrict__ g1,
    const float* __restrict__ g2, const float* __restrict__ Wq,
    double* __restrict__ Qh4)
{
    __shared__ float As[32][34];   // [row][k], pad 34 -> 8B-aligned rows
    __shared__ float Ws[32][34];   // [col][k]
    const int t  = threadIdx.x;
    const int tx = t & 15, ty = t >> 4;
    const int i0 = blockIdx.y * 32, j0 = blockIdx.x * 32;
    const int kc = blockIdx.z;
    double a00 = 0, a01 = 0, a10 = 0, a11 = 0;
    for (int kk = kc * KCH; kk < kc * KCH + KCH; kk += 32) {
        for (int s = 0; s < 4; ++s) {
            int idx = t + s * 256;
            int r = idx >> 5, c = idx & 31;
            int row = i0 + r;
            int b = row / 3, q = row - b * 3;
            const float* gp = (q == 0) ? g0 : (q == 1) ? g1 : g2;
            As[r][c] = gp[b * DD + kk + c];
            Ws[r][c] = Wq[(j0 + r) * DD + kk + c];
        }
        __syncthreads();
        #pragma unroll
        for (int k = 0; k < 32; k += 2) {
            vfloat2 xa = *(const vfloat2*)&As[ty][k];
            vfloat2 xb = *(const vfloat2*)&As[ty + 16][k];
            vfloat2 ya = *(const vfloat2*)&Ws[tx][k];
            vfloat2 yb = *(const vfloat2*)&Ws[tx + 16][k];
            // k
            a00 += (double)xa[0] * (double)ya[0];
            a01 += (double)xa[0] * (double)yb[0];
            a10 += (double)xb[0] * (double)ya[0];
            a11 += (double)xb[0] * (double)yb[0];
            // k+1
            a00 += (double)xa[1] * (double)ya[1];
            a01 += (double)xa[1] * (double)yb[1];
            a10 += (double)xb[1] * (double)ya[1];
            a11 += (double)xb[1] * (double)yb[1];
        }
        __syncthreads();
    }
    double* Q = Qh4 + (size_t)kc * MAT;
    Q[(i0 + ty) * DD + j0 + tx]           = a00;
    Q[(i0 + ty) * DD + j0 + tx + 16]      = a01;
    Q[(i0 + ty + 16) * DD + j0 + tx]      = a10;
    Q[(i0 + ty + 16) * DD + j0 + tx + 16] = a11;
}

// ---------------------------------------------------------------------------
// Reduce Qh partials (fixed order 0..3) + bias -> Qh[r][e]
// ---------------------------------------------------------------------------
__global__ __launch_bounds__(256) void reduce_q(
    const double* __restrict__ Qh4, const float* __restrict__ bq,
    double* __restrict__ Qh)
{
    const int i = blockIdx.x * 256 + threadIdx.x;   // 0..589823
    const int e = i - (i / DD) * DD;                // column = e index
    double s = ((Qh4[i] + Qh4[i + MAT]) + Qh4[i + 2 * MAT]) + Qh4[i + 3 * MAT];
    Qh[i] = s + (double)bq[e];
}

// ---------------------------------------------------------------------------
// GEMM2 split-K: Td4[kc][r][d] = sum_{e in chunk kc} Qh[r,e]*Wk[e,d]
// A (fp64) read as double2 (ds_read_b128); Ws staged TRANSPOSED [col][k]
// so B k-pairs are float2 reads. Same global access pattern as round 4.
// ---------------------------------------------------------------------------
__global__ __launch_bounds__(256) void gemm_t_sk(
    const double* __restrict__ Qh, const float* __restrict__ Wk,
    double* __restrict__ Td4)
{
    __shared__ double Ast[32][34];  // [row][k], pad 34 -> 16B-aligned rows
    __shared__ float  Wst[32][34];  // [col][k]
    const int t  = threadIdx.x;
    const int tx = t & 15, ty = t >> 4;
    const int i0 = blockIdx.y * 32, j0 = blockIdx.x * 32;
    const int kc = blockIdx.z;
    double a00 = 0, a01 = 0, a10 = 0, a11 = 0;
    for (int kk = kc * KCH; kk < kc * KCH + KCH; kk += 32) {
        for (int s = 0; s < 4; ++s) {
            int idx = t + s * 256;
            int r = idx >> 5, c = idx & 31;
            Ast[r][c] = Qh[(i0 + r) * DD + kk + c];     // [row][k]
            Wst[c][r] = Wk[(kk + r) * DD + j0 + c];     // transpose -> [col][k]
        }
        __syncthreads();
        #pragma unroll
        for (int k = 0; k < 32; k += 2) {
            vdouble2 xa = *(const vdouble2*)&Ast[ty][k];
            vdouble2 xb = *(const vdouble2*)&Ast[ty + 16][k];
            vfloat2  ya = *(const vfloat2*)&Wst[tx][k];
            vfloat2  yb = *(const vfloat2*)&Wst[tx + 16][k];
            // k
            a00 += xa[0] * (double)ya[0];
            a01 += xa[0] * (double)yb[0];
            a10 += xb[0] * (double)ya[0];
            a11 += xb[0] * (double)yb[0];
            // k+1
            a00 += xa[1] * (double)ya[1];
            a01 += xa[1] * (double)yb[1];
            a10 += xb[1] * (double)ya[1];
            a11 += xb[1] * (double)yb[1];
        }
        __syncthreads();
    }
    double* T = Td4 + (size_t)kc * MAT;
    T[(i0 + ty) * DD + j0 + tx]           = a00;
    T[(i0 + ty) * DD + j0 + tx + 16]      = a01;
    T[(i0 + ty + 16) * DD + j0 + tx]      = a10;
    T[(i0 + ty + 16) * DD + j0 + tx + 16] = a11;
}

// ---------------------------------------------------------------------------
// Fused score + rank + apply: one block per batch b (256 blocks x 1024 thr).
// UNCHANGED from the verified round-4 kernel (absmax 0).
// ---------------------------------------------------------------------------
__global__ __launch_bounds__(1024) void fused_score_rank_apply(
    const float* __restrict__ p0, const float* __restrict__ p1,
    const float* __restrict__ p2, const float* __restrict__ g0,
    const float* __restrict__ g1, const float* __restrict__ g2,
    const double* __restrict__ Td4, float* __restrict__ out)
{
    const int b = blockIdx.x;
    __shared__ float  Gf[3][DD];        //  9.2 KB
    __shared__ double Tq[3][DD];        // 18.4 KB
    __shared__ double Li[3][NN];        //  4.7 KB intra logits
    __shared__ double Le[3][CAND];      //  9.4 KB inter logits
    __shared__ unsigned char msk[3][NN];

    // ---- phase 1: stage globals and reduced Td rows ----
    for (int d = threadIdx.x; d < DD; d += 1024) {
        Gf[0][d] = g0[b * DD + d];
        Gf[1][d] = g1[b * DD + d];
        Gf[2][d] = g2[b * DD + d];
        #pragma unroll
        for (int q = 0; q < 3; ++q) {
            const size_t off = (size_t)(b * 3 + q) * DD + d;
            Tq[q][d] = ((Td4[off] + Td4[off + MAT]) + Td4[off + 2 * MAT])
                     + Td4[off + 3 * MAT];
        }
    }
    if (threadIdx.x < 3 * NN) (&msk[0][0])[threadIdx.x] = 0;
    __syncthreads();

    const int wave = threadIdx.x >> 6, lane = threadIdx.x & 63;

    // ---- phase 2: score all 588 rows, copy patch -> out on the fly ----
    for (int r = wave; r < 3 * NN; r += 16) {
        const int m = r / NN, n = r - m * NN;
        const float* pp = (m == 0) ? p0 : (m == 1) ? p1 : p2;
        const vfloat4* row = (const vfloat4*)(pp + (size_t)(b * NN + n) * DD);
        vfloat4* orow = (vfloat4*)(out + ((size_t)m * (BB * NN) + b * NN + n) * (size_t)DD);
        const int qa = (m == 0) ? 1 : 0;
        const int qb = (m == 2) ? 1 : 2;
        const int slota = m - (m > qa ? 1 : 0);
        const int slotb = m - (m > qb ? 1 : 0);
        double s0 = 0, s1 = 0, s2 = 0;
        for (int c = lane; c < DD / 4; c += 64) {
            vfloat4 v = row[c];
            __builtin_nontemporal_store(v, &orow[c]);
            const int d = c * 4;
            s0 += (double)Gf[m][d]     * (double)v[0] + (double)Gf[m][d + 1] * (double)v[1]
                + (double)Gf[m][d + 2] * (double)v[2] + (double)Gf[m][d + 3] * (double)v[3];
            s1 += Tq[qa][d]     * (double)v[0] + Tq[qa][d + 1] * (double)v[1]
                + Tq[qa][d + 2] * (double)v[2] + Tq[qa][d + 3] * (double)v[3];
            s2 += Tq[qb][d]     * (double)v[0] + Tq[qb][d + 1] * (double)v[1]
                + Tq[qb][d + 2] * (double)v[2] + Tq[qb][d + 3] * (double)v[3];
        }
        for (int off = 32; off > 0; off >>= 1) {
            s0 += __shfl_down(s0, off);
            s1 += __shfl_down(s1, off);
            s2 += __shfl_down(s2, off);
        }
        if (lane == 0) {
            Li[m][n] = s0;
            Le[qa][slota * NN + n] = s1;
            Le[qb][slotb * NN + n] = s2;
        }
    }
    __syncthreads();

    // ---- phase 3a: intra ranks ----
    if (threadIdx.x < 3 * NN) {
        const int m = threadIdx.x / NN, n = threadIdx.x - m * NN;
        const double v = Li[m][n];
        int rank = 0;
        for (int j = 0; j < NN; ++j) {
            double u = Li[m][j];
            rank += (u > v) || (u == v && j < n);
        }
        if (rank < KK1) msk[m][n] = 1;
    }
    // ---- phase 3b: inter ranks ----
    for (int t = threadIdx.x; t < 3 * CAND; t += 1024) {
        const int q = t / CAND, c = t - q * CAND;
        const double v = Le[q][c];
        int rank = 0;
        for (int j = 0; j < CAND; ++j) {
            double u = Le[q][j];
            rank += (u > v) || (u == v && j < c);
        }
        if (rank < KK2) {
            const int ma = (q == 0) ? 1 : 0;
            const int mb = (q == 2) ? 1 : 2;
            const int mm  = (c < NN) ? ma : mb;
            const int tok = (c < NN) ? c : c - NN;
            msk[mm][tok] = 1;   // only ever writes 1; benign races
        }
    }
    __syncthreads();

    // ---- phase 4: zero the unselected rows ----
    for (int r = wave; r < 3 * NN; r += 16) {
        const int m = r / NN, n = r - m * NN;
        if (!msk[m][n]) {
            vfloat4* orow = (vfloat4*)(out + ((size_t)m * (BB * NN) + b * NN + n) * (size_t)DD);
            const vfloat4 z = {0.f, 0.f, 0.f, 0.f};
            for (int c = lane; c < DD / 4; c += 64)
                __builtin_nontemporal_store(z, &orow[c]);
        }
    }
}

extern "C" void kernel_launch(void* const* d_in, const int* in_sizes, int n_in,
                              void* d_out, int out_size, void* d_ws, size_t ws_size,
                              hipStream_t stream) {
    const float* p0 = (const float*)d_in[0];   // rgb_patches
    const float* p1 = (const float*)d_in[1];   // nir_patches
    const float* p2 = (const float*)d_in[2];   // tir_patches
    const float* g0 = (const float*)d_in[3];   // rgb_global
    const float* g1 = (const float*)d_in[4];   // nir_global
    const float* g2 = (const float*)d_in[5];   // tir_global
    const float* Wq = (const float*)d_in[6];
    const float* bq = (const float*)d_in[7];
    const float* Wk = (const float*)d_in[8];
    // d_in[9] = bk: per-(b,q)-row constant across all candidates -> cannot
    // affect top-k ordering; intentionally unused.

    char* ws = (char*)d_ws;
    double* Qh4 = (double*)(ws);
    double* Qh  = (double*)(ws + 18874368);
    double* Td4 = (double*)(ws + 23592960);

    dim3 ggrid(DD / 32, RTOT / 32, NSK);   // (24, 24, 4)
    gemm_q_sk<<<ggrid, 256, 0, stream>>>(g0, g1, g2, Wq, Qh4);
    reduce_q<<<MAT / 256, 256, 0, stream>>>(Qh4, bq, Qh);
    gemm_t_sk<<<ggrid, 256, 0, stream>>>(Qh, Wk, Td4);
    fused_score_rank_apply<<<BB, 1024, 0, stream>>>(p0, p1, p2, g0, g1, g2, Td4, (float*)d_out);
}